// Round 5
// baseline (1025.593 us; speedup 1.0000x reference)
//
#include <hip/hip_runtime.h>
#include <cstdint>
#include <cstddef>

#define NN 100000
#define NE 1600000
#define NB 25        // dst buckets of 4096 nodes (100000 >> 12 = 24 max)

typedef short short8 __attribute__((ext_vector_type(8)));
typedef float floatx4 __attribute__((ext_vector_type(4)));

// ---------------- graph preprocessing ----------------

static __global__ void k_init_deg(int* __restrict__ deg, int* __restrict__ gh) {
    int i = blockIdx.x * 256 + threadIdx.x;
    if (i < NN) deg[i] = 1;  // self loop
    if (i < 32) gh[i] = 0;   // bucket histogram zero-init (ws is 0xAA-poisoned)
}

static __global__ void k_count(const int* __restrict__ dst, int* __restrict__ deg) {
    int e = blockIdx.x * 256 + threadIdx.x;
    if (e < NE) atomicAdd(&deg[dst[e]], 1);
}

static __global__ void k_dinv(const int* __restrict__ deg, float* __restrict__ dinv) {
    int i = blockIdx.x * 256 + threadIdx.x;
    if (i < NN) dinv[i] = rsqrtf((float)deg[i]);  // deg >= 1 always
}

// exclusive scan of (deg[i]-1) -> row_ptr, chunk=1024/block
static __global__ void k_scan1(const int* __restrict__ deg, int* __restrict__ row_ptr,
                               int* __restrict__ bsums) {
    __shared__ int sd[256];
    int t = threadIdx.x;
    int base = blockIdx.x * 1024;
    int v[4];
    int s = 0;
#pragma unroll
    for (int j = 0; j < 4; j++) {
        int i = base + t * 4 + j;
        int c = (i < NN) ? (deg[i] - 1) : 0;
        v[j] = s;
        s += c;
    }
    sd[t] = s;
    __syncthreads();
    for (int off = 1; off < 256; off <<= 1) {
        int x = (t >= off) ? sd[t - off] : 0;
        __syncthreads();
        sd[t] += x;
        __syncthreads();
    }
    int excl = (t > 0) ? sd[t - 1] : 0;
#pragma unroll
    for (int j = 0; j < 4; j++) {
        int i = base + t * 4 + j;
        if (i < NN) row_ptr[i] = excl + v[j];
    }
    if (t == 255) bsums[blockIdx.x] = sd[255];
}

static __global__ void k_scan2(int* __restrict__ bsums, int nb) {
    if (blockIdx.x == 0 && threadIdx.x == 0) {
        int s = 0;
        for (int i = 0; i < nb; i++) {
            int c = bsums[i];
            bsums[i] = s;
            s += c;
        }
    }
}

static __global__ void k_scan3(int* __restrict__ row_ptr, int* __restrict__ cursor,
                               const int* __restrict__ bsums) {
    int i = blockIdx.x * 256 + threadIdx.x;
    if (i < NN) {
        int v = row_ptr[i] + bsums[i >> 10];
        row_ptr[i] = v;
        cursor[i] = v;
    } else if (i == NN) {
        row_ptr[NN] = NE;
    }
}

// ---- bucketed CSR fill (replaces single-pass k_fill: 105 MB of random 4B
// scatter writes = 16x amplification, 127 us). Bucket by dst>>12 so the fill
// phase's cursor table (16 KB) and csr segment (~256 KB) are L2-resident. ----

// per-block LDS histogram -> global bucket histogram
static __global__ void k_bhist(const int* __restrict__ dst, int* __restrict__ gh) {
    __shared__ int h[32];
    int t = threadIdx.x;
    if (t < 32) h[t] = 0;
    __syncthreads();
    int e = blockIdx.x * 256 + t;
    if (e < NE) atomicAdd(&h[dst[e] >> 12], 1);
    __syncthreads();
    if (t < NB && h[t]) atomicAdd(&gh[t], h[t]);
}

// tiny exclusive scan of 25 buckets
static __global__ void k_bscan(const int* __restrict__ gh, int* __restrict__ gbase,
                               int* __restrict__ gcur) {
    if (threadIdx.x == 0 && blockIdx.x == 0) {
        int s = 0;
        for (int b = 0; b < NB; b++) {
            gbase[b] = s;
            gcur[b] = s;
            s += gh[b];
        }
        gbase[NB] = s;  // == NE
    }
}

// scatter edges into bucket-ordered staging (int2 = src,dst); per-block LDS
// histogram + one global cursor bump per bucket -> writes are ~25 contiguous
// chunks per block instead of 1.6M random 4B scatters.
static __global__ __launch_bounds__(1024) void k_bscatter(const int* __restrict__ src,
                                                          const int* __restrict__ dst,
                                                          int* __restrict__ gcur,
                                                          int2* __restrict__ staging) {
    __shared__ int h[32];
    __shared__ int base[32];
    int t = threadIdx.x;
    if (t < 32) h[t] = 0;
    __syncthreads();
    int e = blockIdx.x * 1024 + t;
    int b = -1, l = 0, sv = 0, dv = 0;
    if (e < NE) {
        sv = src[e];
        dv = dst[e];
        b = dv >> 12;
        l = atomicAdd(&h[b], 1);
    }
    __syncthreads();
    if (t < NB && h[t]) base[t] = atomicAdd(&gcur[t], h[t]);
    __syncthreads();
    if (e < NE) staging[base[b] + l] = make_int2(sv, dv);
}

// per-bucket fill: one block per bucket; cursor+csr region L2-resident
static __global__ __launch_bounds__(1024) void k_bfill(const int2* __restrict__ staging,
                                                       const int* __restrict__ gbase,
                                                       int* __restrict__ cursor,
                                                       int* __restrict__ csr_src) {
    int b = blockIdx.x;
    int end = gbase[b + 1];
    for (int i = gbase[b] + threadIdx.x; i < end; i += 1024) {
        int2 ed = staging[i];
        int pos = atomicAdd(&cursor[ed.y], 1);
        csr_src[pos] = ed.x;
    }
}

// ---------------- split-bf16 helper ----------------
// f = hi + lo + eps, eps ~ 2^-18 rel. RNE rounding to bf16.
__device__ __forceinline__ void split_bf16(float f, short& hi, short& lo) {
    union { float f; uint32_t u; } x;
    x.f = f;
    uint32_t uh = x.u + 0x7FFFu + ((x.u >> 16) & 1u);
    hi = (short)(uh >> 16);
    union { uint32_t u; float f; } hf;
    hf.u = (uh >> 16) << 16;
    float r = f - hf.f;
    union { float f; uint32_t u; } y;
    y.f = r;
    uint32_t ul = y.u + 0x7FFFu + ((y.u >> 16) & 1u);
    lo = (short)(ul >> 16);
}

// ---------------- weight pre-split into MFMA B-fragment layout ----------------
// B operand layout (verified round-4 pass): lane = kq*16+r16 holds
// B[k = ks*32 + kq*8 + j][n = ntile*16 + r16], j=0..7.
// Frag array: fh[((ntile*KST + ks)*64 + lane)*8 + j], KST = DIN/32.
// One fused kernel preps all 6 weights (W total ~280 KB; runs every call).
struct WDesc {
    const float* W;
    short* fh;
    short* fl;
    int din, dout, transb, base, total;  // base/total in units of short8 groups
};
struct WPrepArgs { WDesc d[6]; };

static __global__ void k_wprep(WPrepArgs args) {
    int tid = blockIdx.x * 256 + threadIdx.x;
#pragma unroll
    for (int i = 0; i < 6; i++) {
        const WDesc& D = args.d[i];
        if (tid >= D.base && tid < D.base + D.total) {
            int local = tid - D.base;
            int lane = local & 63;
            int rest = local >> 6;
            int kst = D.din >> 5;
            int ks = rest % kst;
            int ntile = rest / kst;
            int n = ntile * 16 + (lane & 15);
            int k0 = ks * 32 + (lane >> 4) * 8;
#pragma unroll
            for (int j = 0; j < 8; j++) {
                int k = k0 + j;
                float v = D.transb ? D.W[(size_t)n * D.din + k]
                                   : D.W[(size_t)k * D.dout + n];
                short h, l;
                split_bf16(v, h, l);
                D.fh[(size_t)local * 8 + j] = h;
                D.fl[(size_t)local * 8 + j] = l;
            }
        }
    }
}

// ---------------- MFMA GEMM: LDS-free, B-fragments in registers ----------------
// Each wave owns one 16-col N-tile; B frags (hi/lo) live in VGPRs across the
// whole M loop. A is fp32, loaded coalesced and split in-register. 3 MFMAs per
// k-step: hi*hi + hi*lo + lo*hi (lo*lo dropped, ~2^-18 rel).
// No LDS, no barriers (round-4 lesson: per-block W staging had 8-way LDS
// write conflicts + 2 barriers/phase and was redone 1563x).
// NOTE round-2 lesson: do NOT add aggressive __launch_bounds__ occupancy
// minimums; VGPR cap below need -> scratch spill -> 30x write amplification.
template <int DIN, int DOUT, bool RESID, bool BIAS, bool SCALE>
__global__ __launch_bounds__(256) void k_mgemm(const float* __restrict__ A,
                                               const short* __restrict__ fh,
                                               const short* __restrict__ fl,
                                               const float* __restrict__ bias,
                                               const float* __restrict__ dinv,
                                               float* __restrict__ C) {
    static_assert(!RESID || DIN == DOUT, "residual needs square");
    constexpr int KST = DIN / 32;
    const int t = threadIdx.x;
    const int wave = t >> 6;
    const int lane = t & 63;
    const int r16 = lane & 15;
    const int kq = lane >> 4;
    const int ntile = blockIdx.y * 4 + wave;
    const int col = ntile * 16 + r16;

    short8 bh[KST], bl[KST];
#pragma unroll
    for (int ks = 0; ks < KST; ks++) {
        size_t o = ((size_t)(ntile * KST + ks) * 64 + lane) * 8;
        bh[ks] = *(const short8*)(fh + o);
        bl[ks] = *(const short8*)(fl + o);
    }

    const int m0b = blockIdx.x * 128;
#pragma unroll 1
    for (int mt = 0; mt < 8; mt++) {
        const int m0 = m0b + mt * 16;
        if (m0 >= NN) break;
        const int ra = min(m0 + r16, NN - 1);  // clamp; stores guarded
        const float* Ap = A + (size_t)ra * DIN + kq * 8;

        floatx4 acc = {0.f, 0.f, 0.f, 0.f};
#pragma unroll
        for (int ks = 0; ks < KST; ks++) {
            float4 f0 = *(const float4*)(Ap + ks * 32);
            float4 f1 = *(const float4*)(Ap + ks * 32 + 4);
            float fe[8] = {f0.x, f0.y, f0.z, f0.w, f1.x, f1.y, f1.z, f1.w};
            short8 ah, al;
#pragma unroll
            for (int j = 0; j < 8; j++) {
                short h, l;
                split_bf16(fe[j], h, l);
                ah[j] = h;
                al[j] = l;
            }
            acc = __builtin_amdgcn_mfma_f32_16x16x32_bf16(ah, bh[ks], acc, 0, 0, 0);
            acc = __builtin_amdgcn_mfma_f32_16x16x32_bf16(ah, bl[ks], acc, 0, 0, 0);
            acc = __builtin_amdgcn_mfma_f32_16x16x32_bf16(al, bh[ks], acc, 0, 0, 0);
        }

        // C/D layout: row = kq*4 + r, col = r16 (verified)
#pragma unroll
        for (int r = 0; r < 4; r++) {
            int row = m0 + kq * 4 + r;
            if (row < NN) {
                float v = acc[r];
                if constexpr (RESID) v = fmaxf(v + A[(size_t)row * DIN + col], 0.f);
                if constexpr (BIAS)  v = fmaxf(v + bias[col], 0.f);
                if constexpr (SCALE) v *= dinv[row];
                C[(size_t)row * DOUT + col] = v;
            }
        }
    }
}

// ---------------- GCN aggregation (unchanged this round) ----------------
template <int D, bool BIAS_RELU>
__global__ __launch_bounds__(256) void k_agg(const float* __restrict__ hs,
                                             const float* __restrict__ dinv,
                                             const int* __restrict__ row_ptr,
                                             const int* __restrict__ csr_src,
                                             const float* __restrict__ bias,
                                             float* __restrict__ out) {
    constexpr int V = D / 64;
    int node = blockIdx.x * 4 + (threadIdx.x >> 6);
    int lane = threadIdx.x & 63;
    if (node >= NN) return;
    const int off = lane * V;

    float a0, a1 = 0.f;
    {
        const float* p = hs + (size_t)node * D + off;
        if constexpr (V == 2) { float2 v = *(const float2*)p; a0 = v.x; a1 = v.y; }
        else a0 = *p;
    }

    int e = row_ptr[node];
    const int end = row_ptr[node + 1];

    for (; e + 8 <= end; e += 8) {
        int s[8];
#pragma unroll
        for (int i = 0; i < 8; i++) s[i] = csr_src[e + i];
        if constexpr (V == 2) {
            float2 v[8];
#pragma unroll
            for (int i = 0; i < 8; i++) v[i] = *(const float2*)(hs + (size_t)s[i] * D + off);
#pragma unroll
            for (int i = 0; i < 8; i++) { a0 += v[i].x; a1 += v[i].y; }
        } else {
            float v[8];
#pragma unroll
            for (int i = 0; i < 8; i++) v[i] = hs[(size_t)s[i] * D + off];
#pragma unroll
            for (int i = 0; i < 8; i++) a0 += v[i];
        }
    }
    for (; e + 4 <= end; e += 4) {
        int s[4];
#pragma unroll
        for (int i = 0; i < 4; i++) s[i] = csr_src[e + i];
        if constexpr (V == 2) {
            float2 v[4];
#pragma unroll
            for (int i = 0; i < 4; i++) v[i] = *(const float2*)(hs + (size_t)s[i] * D + off);
#pragma unroll
            for (int i = 0; i < 4; i++) { a0 += v[i].x; a1 += v[i].y; }
        } else {
            float v[4];
#pragma unroll
            for (int i = 0; i < 4; i++) v[i] = hs[(size_t)s[i] * D + off];
#pragma unroll
            for (int i = 0; i < 4; i++) a0 += v[i];
        }
    }
    for (; e < end; e++) {
        int s = csr_src[e];
        const float* p = hs + (size_t)s * D + off;
        if constexpr (V == 2) { float2 v = *(const float2*)p; a0 += v.x; a1 += v.y; }
        else a0 += *p;
    }

    const float di = dinv[node];
    a0 *= di;
    if constexpr (V == 2) a1 *= di;
    if constexpr (BIAS_RELU) {
        a0 = fmaxf(a0 + bias[off], 0.f);
        if constexpr (V == 2) a1 = fmaxf(a1 + bias[off + 1], 0.f);
    }
    float* po = out + (size_t)node * D + off;
    if constexpr (V == 2) { *(float2*)po = make_float2(a0, a1); }
    else *po = a0;
}

// ---------------- launch ----------------

extern "C" void kernel_launch(void* const* d_in, const int* in_sizes, int n_in,
                              void* d_out, int out_size, void* d_ws, size_t ws_size,
                              hipStream_t stream) {
    const float* x   = (const float*)d_in[0];
    const int*   ei  = (const int*)d_in[1];
    const float* g1w = (const float*)d_in[2];
    const float* g1b = (const float*)d_in[3];
    const float* f2w = (const float*)d_in[4];
    const float* g3w = (const float*)d_in[5];
    const float* g3b = (const float*)d_in[6];
    const float* f4w = (const float*)d_in[7];
    const float* g5w = (const float*)d_in[8];
    const float* g5b = (const float*)d_in[9];
    const float* f6w = (const float*)d_in[10];
    float* out = (float*)d_out;

    const int* src = ei;       // edge_index[0]
    const int* dst = ei + NE;  // edge_index[1]

    char* p = (char*)d_ws;
    auto alloc = [&](size_t bytes) -> void* {
        void* r = (void*)p;
        p += (bytes + 255) & ~(size_t)255;
        return r;
    };
    int*   deg     = (int*)alloc(NN * 4);
    float* dinv    = (float*)alloc(NN * 4);
    int*   row_ptr = (int*)alloc((NN + 1) * 4);
    int*   cursor  = (int*)alloc(NN * 4);
    int*   bsums   = (int*)alloc(512);
    int*   gh      = (int*)alloc(128);
    int*   gbase   = (int*)alloc(128);
    int*   gcur    = (int*)alloc(128);
    int*   csr     = (int*)alloc(NE * 4);
    short* wfh     = (short*)alloc(69632 * 2);
    short* wfl     = (short*)alloc(69632 * 2);
    float* bufA    = (float*)alloc((size_t)NN * 128 * 4);
    float* bufB    = (float*)alloc((size_t)NN * 128 * 4);
    // edge staging (12.8 MB) aliases bufB: consumed by k_bfill before the
    // first write to bufB (agg1), stream-ordered.
    int2* staging  = (int2*)bufB;

    const int gN  = (NN + 255) / 256;
    const int gE  = (NE + 255) / 256;
    const int gS  = (NN + 1023) / 1024;
    const int gN1 = (NN + 1 + 255) / 256;
    const int gA  = NN / 4;                  // 25000
    const int gM  = (NN + 127) / 128;        // 782

    // graph preprocessing
    k_init_deg<<<gN, 256, 0, stream>>>(deg, gh);
    k_count<<<gE, 256, 0, stream>>>(dst, deg);
    k_dinv<<<gN, 256, 0, stream>>>(deg, dinv);
    k_scan1<<<gS, 256, 0, stream>>>(deg, row_ptr, bsums);
    k_scan2<<<1, 64, 0, stream>>>(bsums, gS);
    k_scan3<<<gN1, 256, 0, stream>>>(row_ptr, cursor, bsums);
    k_bhist<<<gE, 256, 0, stream>>>(dst, gh);
    k_bscan<<<1, 64, 0, stream>>>(gh, gbase, gcur);
    k_bscatter<<<(NE + 1023) / 1024, 1024, 0, stream>>>(src, dst, gcur, staging);
    k_bfill<<<NB, 1024, 0, stream>>>(staging, gbase, cursor, csr);

    // weight fragment prep (offsets in short8 groups: elems/8 prefix sums)
    {
        WPrepArgs a;
        // elems: g1 16384, fc2 16384, g3 8192, fc4 4096, g5 8192, fc6 16384
        int  eoff[6] = {0, 16384, 32768, 40960, 45056, 53248};
        int  base[6] = {0, 2048, 4096, 5120, 5632, 6656};
        int  tot[6]  = {2048, 2048, 1024, 512, 1024, 2048};
        const float* Ws[6] = {g1w, f2w, g3w, f4w, g5w, f6w};
        int din[6]  = {128, 128, 128, 64, 64, 128};
        int dout[6] = {128, 128, 64, 64, 128, 128};
        int trb[6]  = {0, 1, 0, 1, 0, 1};
        for (int i = 0; i < 6; i++) {
            a.d[i] = WDesc{Ws[i], wfh + eoff[i], wfl + eoff[i],
                           din[i], dout[i], trb[i], base[i], tot[i]};
        }
        k_wprep<<<(8704 + 255) / 256, 256, 0, stream>>>(a);
    }

    // layer 1: hs1 = dinv*(x@W1); z1 = relu(dinv*agg(hs1)+b1); z1' = relu(z1 + z1@fc2^T)
    k_mgemm<128, 128, false, false, true><<<dim3(gM, 2), 256, 0, stream>>>(
        x, wfh + 0, wfl + 0, nullptr, dinv, bufA);
    k_agg<128, true><<<gA, 256, 0, stream>>>(bufA, dinv, row_ptr, csr, g1b, bufB);
    k_mgemm<128, 128, true, false, false><<<dim3(gM, 2), 256, 0, stream>>>(
        bufB, wfh + 16384, wfl + 16384, nullptr, nullptr, bufA);

    // layer 2
    k_mgemm<128, 64, false, false, true><<<dim3(gM, 1), 256, 0, stream>>>(
        bufA, wfh + 32768, wfl + 32768, nullptr, dinv, bufB);
    k_agg<64, true><<<gA, 256, 0, stream>>>(bufB, dinv, row_ptr, csr, g3b, bufA);
    k_mgemm<64, 64, true, false, true><<<dim3(gM, 1), 256, 0, stream>>>(
        bufA, wfh + 40960, wfl + 40960, nullptr, dinv, bufB);

    // layer 3 (reordered: aggregate at 64ch, then GEMM)
    k_agg<64, false><<<gA, 256, 0, stream>>>(bufB, dinv, row_ptr, csr, nullptr, bufA);
    k_mgemm<64, 128, false, true, false><<<dim3(gM, 2), 256, 0, stream>>>(
        bufA, wfh + 45056, wfl + 45056, g5b, nullptr, bufB);
    k_mgemm<128, 128, true, false, false><<<dim3(gM, 2), 256, 0, stream>>>(
        bufB, wfh + 53248, wfl + 53248, nullptr, nullptr, out);
}

// Round 6
// 699.022 us; speedup vs baseline: 1.4672x; 1.4672x over previous
//
#include <hip/hip_runtime.h>
#include <cstdint>
#include <cstddef>

#define NN 100000
#define NE 1600000
#define NBB 391   // dst buckets of 256 nodes: ceil(100000/256)

typedef short short8 __attribute__((ext_vector_type(8)));
typedef float floatx4 __attribute__((ext_vector_type(4)));

// ---------------- graph preprocessing (bucketed, atomic-light) ----------------
// Round-5 lesson: 25-bucket k_bfill = 4% occupancy (25 blocks) -> 189 us.
// Bucket at 256-node granularity (391 blocks), ranks via LDS atomics.

static __global__ void k_zero(int* __restrict__ gh) {
    int i = threadIdx.x;
    if (i < NBB + 1) gh[i] = 0;
}

// histogram of dst>>8 ; 1024 thr x 4 edges/block -> 391 global atomics/block
static __global__ __launch_bounds__(1024) void k_bhist(const int* __restrict__ dst,
                                                       int* __restrict__ gh) {
    __shared__ int h[NBB + 1];
    int t = threadIdx.x;
    for (int i = t; i < NBB; i += 1024) h[i] = 0;
    __syncthreads();
    int e0 = blockIdx.x * 4096;
#pragma unroll
    for (int j = 0; j < 4; j++) {
        int e = e0 + j * 1024 + t;
        if (e < NE) atomicAdd(&h[dst[e] >> 8], 1);
    }
    __syncthreads();
    for (int i = t; i < NBB; i += 1024)
        if (h[i]) atomicAdd(&gh[i], h[i]);
}

static __global__ void k_bscan(const int* __restrict__ gh, int* __restrict__ gbase,
                               int* __restrict__ gcur) {
    if (threadIdx.x == 0 && blockIdx.x == 0) {
        int s = 0;
        for (int b = 0; b < NBB; b++) {
            gbase[b] = s;
            gcur[b] = s;
            s += gh[b];
        }
        gbase[NBB] = s;  // == NE
    }
}

// scatter edges into bucket-ordered staging (int2 = src,dst)
static __global__ __launch_bounds__(1024) void k_bscatter(const int* __restrict__ src,
                                                          const int* __restrict__ dst,
                                                          int* __restrict__ gcur,
                                                          int2* __restrict__ staging) {
    __shared__ int h[NBB + 1];
    __shared__ int base[NBB + 1];
    int t = threadIdx.x;
    for (int i = t; i < NBB; i += 1024) h[i] = 0;
    __syncthreads();
    int e0 = blockIdx.x * 4096;
    int b[4], l[4], sv[4], dv[4];
#pragma unroll
    for (int j = 0; j < 4; j++) {
        int e = e0 + j * 1024 + t;
        b[j] = -1;
        if (e < NE) {
            sv[j] = src[e];
            dv[j] = dst[e];
            b[j] = dv[j] >> 8;
            l[j] = atomicAdd(&h[b[j]], 1);
        }
    }
    __syncthreads();
    for (int i = t; i < NBB; i += 1024)
        if (h[i]) base[i] = atomicAdd(&gcur[i], h[i]);
    __syncthreads();
#pragma unroll
    for (int j = 0; j < 4; j++)
        if (b[j] >= 0) staging[base[b[j]] + l[j]] = make_int2(sv[j], dv[j]);
}

// per-bucket degree count via LDS -> deg/dinv written coalesced, no global atomics
// (replaces k_init_deg + k_count + k_dinv: k_count was 1.6M random atomics, ~40us)
static __global__ __launch_bounds__(1024) void k_blocal(const int2* __restrict__ staging,
                                                        const int* __restrict__ gbase,
                                                        int* __restrict__ deg,
                                                        float* __restrict__ dinv) {
    __shared__ int cnt[256];
    int b = blockIdx.x;
    int t = threadIdx.x;
    if (t < 256) cnt[t] = 0;
    __syncthreads();
    int end = gbase[b + 1];
    for (int i = gbase[b] + t; i < end; i += 1024)
        atomicAdd(&cnt[staging[i].y & 255], 1);
    __syncthreads();
    if (t < 256) {
        int node = (b << 8) + t;
        if (node < NN) {
            int d = cnt[t] + 1;  // +1 self loop
            deg[node] = d;
            dinv[node] = rsqrtf((float)d);
        }
    }
}

// exclusive scan of (deg[i]-1) -> row_ptr, chunk=1024/block
static __global__ void k_scan1(const int* __restrict__ deg, int* __restrict__ row_ptr,
                               int* __restrict__ bsums) {
    __shared__ int sd[256];
    int t = threadIdx.x;
    int base = blockIdx.x * 1024;
    int v[4];
    int s = 0;
#pragma unroll
    for (int j = 0; j < 4; j++) {
        int i = base + t * 4 + j;
        int c = (i < NN) ? (deg[i] - 1) : 0;
        v[j] = s;
        s += c;
    }
    sd[t] = s;
    __syncthreads();
    for (int off = 1; off < 256; off <<= 1) {
        int x = (t >= off) ? sd[t - off] : 0;
        __syncthreads();
        sd[t] += x;
        __syncthreads();
    }
    int excl = (t > 0) ? sd[t - 1] : 0;
#pragma unroll
    for (int j = 0; j < 4; j++) {
        int i = base + t * 4 + j;
        if (i < NN) row_ptr[i] = excl + v[j];
    }
    if (t == 255) bsums[blockIdx.x] = sd[255];
}

static __global__ void k_scan2(int* __restrict__ bsums, int nb) {
    if (blockIdx.x == 0 && threadIdx.x == 0) {
        int s = 0;
        for (int i = 0; i < nb; i++) {
            int c = bsums[i];
            bsums[i] = s;
            s += c;
        }
    }
}

static __global__ void k_scan3(int* __restrict__ row_ptr, const int* __restrict__ bsums) {
    int i = blockIdx.x * 256 + threadIdx.x;
    if (i < NN) {
        row_ptr[i] += bsums[i >> 10];
    } else if (i == NN) {
        row_ptr[NN] = NE;
    }
}

// per-bucket CSR fill: ranks via LDS atomics, csr writes confined to a 16KB
// L2-hot segment per block; 391 blocks x 16 waves -> ~24 waves/CU
static __global__ __launch_bounds__(1024) void k_bfill(const int2* __restrict__ staging,
                                                       const int* __restrict__ gbase,
                                                       const int* __restrict__ row_ptr,
                                                       int* __restrict__ csr_src) {
    __shared__ int cnt[256];
    int b = blockIdx.x;
    int t = threadIdx.x;
    if (t < 256) cnt[t] = 0;
    __syncthreads();
    int end = gbase[b + 1];
    for (int i = gbase[b] + t; i < end; i += 1024) {
        int2 ed = staging[i];
        int r = atomicAdd(&cnt[ed.y & 255], 1);
        csr_src[row_ptr[ed.y] + r] = ed.x;
    }
}

// ---------------- split-bf16 helper ----------------
__device__ __forceinline__ void split_bf16(float f, short& hi, short& lo) {
    union { float f; uint32_t u; } x;
    x.f = f;
    uint32_t uh = x.u + 0x7FFFu + ((x.u >> 16) & 1u);
    hi = (short)(uh >> 16);
    union { uint32_t u; float f; } hf;
    hf.u = (uh >> 16) << 16;
    float r = f - hf.f;
    union { float f; uint32_t u; } y;
    y.f = r;
    uint32_t ul = y.u + 0x7FFFu + ((y.u >> 16) & 1u);
    lo = (short)(ul >> 16);
}

// ---------------- weight pre-split into MFMA B-fragment layout ----------------
struct WDesc {
    const float* W;
    short* fh;
    short* fl;
    int din, dout, transb, base, total;  // base/total in short8 groups
};
struct WPrepArgs { WDesc d[6]; };

static __global__ void k_wprep(WPrepArgs args) {
    int tid = blockIdx.x * 256 + threadIdx.x;
#pragma unroll
    for (int i = 0; i < 6; i++) {
        const WDesc& D = args.d[i];
        if (tid >= D.base && tid < D.base + D.total) {
            int local = tid - D.base;
            int lane = local & 63;
            int rest = local >> 6;
            int kst = D.din >> 5;
            int ks = rest % kst;
            int ntile = rest / kst;
            int n = ntile * 16 + (lane & 15);
            int k0 = ks * 32 + (lane >> 4) * 8;
#pragma unroll
            for (int j = 0; j < 8; j++) {
                int k = k0 + j;
                float v = D.transb ? D.W[(size_t)n * D.din + k]
                                   : D.W[(size_t)k * D.dout + n];
                short h, l;
                split_bf16(v, h, l);
                D.fh[(size_t)local * 8 + j] = h;
                D.fl[(size_t)local * 8 + j] = l;
            }
        }
    }
}

// ---------------- MFMA GEMM: LDS-free, B in registers, 2 N-tiles/wave ----------
// Block of 4 waves covers ALL DOUT columns (wave owns NTW=DOUT/64 N-tiles) so A
// is read exactly once per GEMM (round-5 read it twice for DOUT=128).
// Frags: NTW*KST*2 short8 = up to 64 VGPRs; total ~110 VGPR, no spill at 256thr.
template <int DIN, int DOUT, bool RESID, bool BIAS, bool SCALE>
__global__ __launch_bounds__(256) void k_mgemm(const float* __restrict__ A,
                                               const short* __restrict__ fh,
                                               const short* __restrict__ fl,
                                               const float* __restrict__ bias,
                                               const float* __restrict__ dinv,
                                               float* __restrict__ C) {
    static_assert(!RESID || DIN == DOUT, "residual needs square");
    constexpr int KST = DIN / 32;
    constexpr int NTW = DOUT / 64;  // N-tiles per wave (block: 4 waves = DOUT/16 tiles)
    const int t = threadIdx.x;
    const int wave = t >> 6;
    const int lane = t & 63;
    const int r16 = lane & 15;
    const int kq = lane >> 4;

    short8 bh[NTW][KST], bl[NTW][KST];
#pragma unroll
    for (int nt = 0; nt < NTW; nt++) {
        int ntile = wave * NTW + nt;
#pragma unroll
        for (int ks = 0; ks < KST; ks++) {
            size_t o = ((size_t)(ntile * KST + ks) * 64 + lane) * 8;
            bh[nt][ks] = *(const short8*)(fh + o);
            bl[nt][ks] = *(const short8*)(fl + o);
        }
    }

    const int m0b = blockIdx.x * 128;
#pragma unroll 1
    for (int mt = 0; mt < 8; mt++) {
        const int m0 = m0b + mt * 16;
        if (m0 >= NN) break;
        const int ra = min(m0 + r16, NN - 1);  // clamp; stores guarded
        const float* Ap = A + (size_t)ra * DIN + kq * 8;

        floatx4 acc[NTW];
#pragma unroll
        for (int nt = 0; nt < NTW; nt++) acc[nt] = (floatx4){0.f, 0.f, 0.f, 0.f};

#pragma unroll
        for (int ks = 0; ks < KST; ks++) {
            float4 f0 = *(const float4*)(Ap + ks * 32);
            float4 f1 = *(const float4*)(Ap + ks * 32 + 4);
            float fe[8] = {f0.x, f0.y, f0.z, f0.w, f1.x, f1.y, f1.z, f1.w};
            short8 ah, al;
#pragma unroll
            for (int j = 0; j < 8; j++) {
                short h, l;
                split_bf16(fe[j], h, l);
                ah[j] = h;
                al[j] = l;
            }
#pragma unroll
            for (int nt = 0; nt < NTW; nt++) {
                acc[nt] = __builtin_amdgcn_mfma_f32_16x16x32_bf16(ah, bh[nt][ks], acc[nt], 0, 0, 0);
                acc[nt] = __builtin_amdgcn_mfma_f32_16x16x32_bf16(ah, bl[nt][ks], acc[nt], 0, 0, 0);
                acc[nt] = __builtin_amdgcn_mfma_f32_16x16x32_bf16(al, bh[nt][ks], acc[nt], 0, 0, 0);
            }
        }

        // C/D layout: row = kq*4 + r, col = r16 (verified)
#pragma unroll
        for (int nt = 0; nt < NTW; nt++) {
            int col = (wave * NTW + nt) * 16 + r16;
#pragma unroll
            for (int r = 0; r < 4; r++) {
                int row = m0 + kq * 4 + r;
                if (row < NN) {
                    float v = acc[nt][r];
                    if constexpr (RESID) v = fmaxf(v + A[(size_t)row * DIN + col], 0.f);
                    if constexpr (BIAS)  v = fmaxf(v + bias[col], 0.f);
                    if constexpr (SCALE) v *= dinv[row];
                    C[(size_t)row * DOUT + col] = v;
                }
            }
        }
    }
}

// ---------------- GCN aggregation (unchanged) ----------------
template <int D, bool BIAS_RELU>
__global__ __launch_bounds__(256) void k_agg(const float* __restrict__ hs,
                                             const float* __restrict__ dinv,
                                             const int* __restrict__ row_ptr,
                                             const int* __restrict__ csr_src,
                                             const float* __restrict__ bias,
                                             float* __restrict__ out) {
    constexpr int V = D / 64;
    int node = blockIdx.x * 4 + (threadIdx.x >> 6);
    int lane = threadIdx.x & 63;
    if (node >= NN) return;
    const int off = lane * V;

    float a0, a1 = 0.f;
    {
        const float* p = hs + (size_t)node * D + off;
        if constexpr (V == 2) { float2 v = *(const float2*)p; a0 = v.x; a1 = v.y; }
        else a0 = *p;
    }

    int e = row_ptr[node];
    const int end = row_ptr[node + 1];

    for (; e + 8 <= end; e += 8) {
        int s[8];
#pragma unroll
        for (int i = 0; i < 8; i++) s[i] = csr_src[e + i];
        if constexpr (V == 2) {
            float2 v[8];
#pragma unroll
            for (int i = 0; i < 8; i++) v[i] = *(const float2*)(hs + (size_t)s[i] * D + off);
#pragma unroll
            for (int i = 0; i < 8; i++) { a0 += v[i].x; a1 += v[i].y; }
        } else {
            float v[8];
#pragma unroll
            for (int i = 0; i < 8; i++) v[i] = hs[(size_t)s[i] * D + off];
#pragma unroll
            for (int i = 0; i < 8; i++) a0 += v[i];
        }
    }
    for (; e + 4 <= end; e += 4) {
        int s[4];
#pragma unroll
        for (int i = 0; i < 4; i++) s[i] = csr_src[e + i];
        if constexpr (V == 2) {
            float2 v[4];
#pragma unroll
            for (int i = 0; i < 4; i++) v[i] = *(const float2*)(hs + (size_t)s[i] * D + off);
#pragma unroll
            for (int i = 0; i < 4; i++) { a0 += v[i].x; a1 += v[i].y; }
        } else {
            float v[4];
#pragma unroll
            for (int i = 0; i < 4; i++) v[i] = hs[(size_t)s[i] * D + off];
#pragma unroll
            for (int i = 0; i < 4; i++) a0 += v[i];
        }
    }
    for (; e < end; e++) {
        int s = csr_src[e];
        const float* p = hs + (size_t)s * D + off;
        if constexpr (V == 2) { float2 v = *(const float2*)p; a0 += v.x; a1 += v.y; }
        else a0 += *p;
    }

    const float di = dinv[node];
    a0 *= di;
    if constexpr (V == 2) a1 *= di;
    if constexpr (BIAS_RELU) {
        a0 = fmaxf(a0 + bias[off], 0.f);
        if constexpr (V == 2) a1 = fmaxf(a1 + bias[off + 1], 0.f);
    }
    float* po = out + (size_t)node * D + off;
    if constexpr (V == 2) { *(float2*)po = make_float2(a0, a1); }
    else *po = a0;
}

// ---------------- launch ----------------

extern "C" void kernel_launch(void* const* d_in, const int* in_sizes, int n_in,
                              void* d_out, int out_size, void* d_ws, size_t ws_size,
                              hipStream_t stream) {
    const float* x   = (const float*)d_in[0];
    const int*   ei  = (const int*)d_in[1];
    const float* g1w = (const float*)d_in[2];
    const float* g1b = (const float*)d_in[3];
    const float* f2w = (const float*)d_in[4];
    const float* g3w = (const float*)d_in[5];
    const float* g3b = (const float*)d_in[6];
    const float* f4w = (const float*)d_in[7];
    const float* g5w = (const float*)d_in[8];
    const float* g5b = (const float*)d_in[9];
    const float* f6w = (const float*)d_in[10];
    float* out = (float*)d_out;

    const int* src = ei;       // edge_index[0]
    const int* dst = ei + NE;  // edge_index[1]

    char* p = (char*)d_ws;
    auto alloc = [&](size_t bytes) -> void* {
        void* r = (void*)p;
        p += (bytes + 255) & ~(size_t)255;
        return r;
    };
    int*   deg     = (int*)alloc(NN * 4);
    float* dinv    = (float*)alloc(NN * 4);
    int*   row_ptr = (int*)alloc((NN + 1) * 4);
    int*   bsums   = (int*)alloc(512);
    int*   gh      = (int*)alloc((NBB + 1) * 4);
    int*   gbase   = (int*)alloc((NBB + 1) * 4);
    int*   gcur    = (int*)alloc((NBB + 1) * 4);
    int*   csr     = (int*)alloc(NE * 4);
    short* wfh     = (short*)alloc(69632 * 2);
    short* wfl     = (short*)alloc(69632 * 2);
    float* bufA    = (float*)alloc((size_t)NN * 128 * 4);
    float* bufB    = (float*)alloc((size_t)NN * 128 * 4);
    // edge staging (12.8 MB) aliases bufB: fully consumed by k_blocal/k_bfill
    // before agg1 writes bufB (stream-ordered).
    int2* staging  = (int2*)bufB;

    const int gE4 = (NE + 4095) / 4096;      // 391
    const int gS  = (NN + 1023) / 1024;      // 98
    const int gN1 = (NN + 1 + 255) / 256;
    const int gA  = NN / 4;                  // 25000
    const int gM  = (NN + 127) / 128;        // 782

    // graph preprocessing
    k_zero<<<1, 512, 0, stream>>>(gh);
    k_bhist<<<gE4, 1024, 0, stream>>>(dst, gh);
    k_bscan<<<1, 64, 0, stream>>>(gh, gbase, gcur);
    k_bscatter<<<gE4, 1024, 0, stream>>>(src, dst, gcur, staging);
    k_blocal<<<NBB, 1024, 0, stream>>>(staging, gbase, deg, dinv);
    k_scan1<<<gS, 256, 0, stream>>>(deg, row_ptr, bsums);
    k_scan2<<<1, 64, 0, stream>>>(bsums, gS);
    k_scan3<<<gN1, 256, 0, stream>>>(row_ptr, bsums);
    k_bfill<<<NBB, 1024, 0, stream>>>(staging, gbase, row_ptr, csr);

    // weight fragment prep
    {
        WPrepArgs a;
        int  eoff[6] = {0, 16384, 32768, 40960, 45056, 53248};
        int  base[6] = {0, 2048, 4096, 5120, 5632, 6656};
        int  tot[6]  = {2048, 2048, 1024, 512, 1024, 2048};
        const float* Ws[6] = {g1w, f2w, g3w, f4w, g5w, f6w};
        int din[6]  = {128, 128, 128, 64, 64, 128};
        int dout[6] = {128, 128, 64, 64, 128, 128};
        int trb[6]  = {0, 1, 0, 1, 0, 1};
        for (int i = 0; i < 6; i++) {
            a.d[i] = WDesc{Ws[i], wfh + eoff[i], wfl + eoff[i],
                           din[i], dout[i], trb[i], base[i], tot[i]};
        }
        k_wprep<<<(8704 + 255) / 256, 256, 0, stream>>>(a);
    }

    // layer 1: hs1 = dinv*(x@W1); z1 = relu(dinv*agg(hs1)+b1); z1' = relu(z1 + z1@fc2^T)
    k_mgemm<128, 128, false, false, true><<<gM, 256, 0, stream>>>(
        x, wfh + 0, wfl + 0, nullptr, dinv, bufA);
    k_agg<128, true><<<gA, 256, 0, stream>>>(bufA, dinv, row_ptr, csr, g1b, bufB);
    k_mgemm<128, 128, true, false, false><<<gM, 256, 0, stream>>>(
        bufB, wfh + 16384, wfl + 16384, nullptr, nullptr, bufA);

    // layer 2
    k_mgemm<128, 64, false, false, true><<<gM, 256, 0, stream>>>(
        bufA, wfh + 32768, wfl + 32768, nullptr, dinv, bufB);
    k_agg<64, true><<<gA, 256, 0, stream>>>(bufB, dinv, row_ptr, csr, g3b, bufA);
    k_mgemm<64, 64, true, false, true><<<gM, 256, 0, stream>>>(
        bufA, wfh + 40960, wfl + 40960, nullptr, dinv, bufB);

    // layer 3 (reordered: aggregate at 64ch, then GEMM)
    k_agg<64, false><<<gA, 256, 0, stream>>>(bufB, dinv, row_ptr, csr, nullptr, bufA);
    k_mgemm<64, 128, false, true, false><<<gM, 256, 0, stream>>>(
        bufA, wfh + 45056, wfl + 45056, g5b, nullptr, bufB);
    k_mgemm<128, 128, true, false, false><<<gM, 256, 0, stream>>>(
        bufB, wfh + 53248, wfl + 53248, nullptr, nullptr, out);
}